// Round 5
// baseline (277.190 us; speedup 1.0000x reference)
//
#include <hip/hip_runtime.h>
#include <hip/hip_bf16.h>

#define B_ 8
#define N_ 1024
#define DIN 256
#define DOUT 256
#define R_ 4

typedef __attribute__((ext_vector_type(8))) short bf16x8;
typedef __attribute__((ext_vector_type(4))) float f32x4;
typedef __attribute__((ext_vector_type(4))) int i32x4;

__device__ __forceinline__ unsigned short f2bf(float f) {
    union { float f; unsigned int u; } v; v.f = f;
    unsigned int u = v.u;
    u += 0x7fffu + ((u >> 16) & 1u);
    return (unsigned short)(u >> 16);
}
__device__ __forceinline__ float bf2f(unsigned short h) {
    union { float f; unsigned int u; } v; v.u = ((unsigned int)h) << 16;
    return v.f;
}

// async global->LDS, 16B/lane. LDS dest = wave-uniform base + lane*16.
__device__ __forceinline__ void gl_lds16(const void* g, void* l) {
    __builtin_amdgcn_global_load_lds(
        (const __attribute__((address_space(1))) unsigned int*)g,
        (__attribute__((address_space(3))) unsigned int*)l, 16, 0, 0);
}

// ---- k0: swizzle rel_w (f32 [R][D][K]) into bf16 MFMA B-fragment layout ----
__global__ __launch_bounds__(256) void k0_swz(const float* __restrict__ rw,
                                              unsigned short* __restrict__ swzW) {
    int t = blockIdx.x * 256 + threadIdx.x;  // 0..32767
    int lane = t & 63, nb = (t >> 6) & 15, ks = (t >> 10) & 7, r = t >> 13;
    int m = lane & 15, q = lane >> 4;
    const float* src = rw + ((r * DOUT + nb * 16 + m) * DIN) + ks * 32 + q * 8;
    float4 v0 = *(const float4*)src;
    float4 v1 = *(const float4*)(src + 4);
    bf16x8 o;
    o[0] = (short)f2bf(v0.x); o[1] = (short)f2bf(v0.y);
    o[2] = (short)f2bf(v0.z); o[3] = (short)f2bf(v0.w);
    o[4] = (short)f2bf(v1.x); o[5] = (short)f2bf(v1.y);
    o[6] = (short)f2bf(v1.z); o[7] = (short)f2bf(v1.w);
    *(bf16x8*)(swzW + (long)t * 8) = o;
}

// ---- k1: G[j][d] = e[j]*(node@rel_w^T + rel_b)[j][d], B-fragment layout -----
// e[j] = exp(sum_d feats[j][d]*attn_w[256+d]); also stores ebf (bf16 e).
__global__ __launch_bounds__(256) void k1_proj(const float* __restrict__ node,
        const unsigned short* __restrict__ swzW, const float* __restrict__ rel_b,
        const float* __restrict__ attn_w,
        unsigned short* __restrict__ fswz, unsigned short* __restrict__ ebf) {
    __shared__ unsigned short Wbuf[2][8192];
    int bid = blockIdx.x;
    int nt = bid & 15, r = (bid >> 4) & 3, b = bid >> 6;
    int w = threadIdx.x >> 6, lane = threadIdx.x & 63;
    int m = lane & 15, q = lane >> 4;
    int n0 = nt * 64 + w * 16;

    const float* Abase = node + ((b * N_ + n0 + m) * DIN) + q * 8;
    const unsigned short* Wsrc = swzW + r * 65536;

#pragma unroll
    for (int i = 0; i < 4; i++)
        gl_lds16(Wsrc + (w * 4 + i) * 512 + lane * 8, &Wbuf[0][(w * 4 + i) * 512]);

    f32x4 acc[16];
#pragma unroll
    for (int i = 0; i < 16; i++) acc[i] = (f32x4)0.0f;

    float4 a0 = *(const float4*)(Abase);
    float4 a1 = *(const float4*)(Abase + 4);

    for (int ks = 0; ks < 8; ks++) {
        int cur = ks & 1;
        __syncthreads();
        if (ks < 7) {
#pragma unroll
            for (int i = 0; i < 4; i++)
                gl_lds16(Wsrc + ((ks + 1) * 16 + w * 4 + i) * 512 + lane * 8,
                         &Wbuf[cur ^ 1][(w * 4 + i) * 512]);
        }
        bf16x8 af;
        af[0] = (short)f2bf(a0.x); af[1] = (short)f2bf(a0.y);
        af[2] = (short)f2bf(a0.z); af[3] = (short)f2bf(a0.w);
        af[4] = (short)f2bf(a1.x); af[5] = (short)f2bf(a1.y);
        af[6] = (short)f2bf(a1.z); af[7] = (short)f2bf(a1.w);
        if (ks < 7) {
            a0 = *(const float4*)(Abase + (ks + 1) * 32);
            a1 = *(const float4*)(Abase + (ks + 1) * 32 + 4);
        }
#pragma unroll
        for (int nb = 0; nb < 16; nb++) {
            bf16x8 wf = *(const bf16x8*)(&Wbuf[cur][nb * 512 + lane * 8]);
            acc[nb] = __builtin_amdgcn_mfma_f32_16x16x32_bf16(af, wf, acc[nb], 0, 0, 0);
        }
    }

    // C layout: row j = n0 + q*4 + reg, col d = nb*16 + m.
    float sj0 = 0.f, sj1 = 0.f, sj2 = 0.f, sj3 = 0.f;
    float bias[16], aw[16];
#pragma unroll
    for (int nb = 0; nb < 16; nb++) {
        int d = nb * 16 + m;
        bias[nb] = rel_b[r * DOUT + d];
        aw[nb] = attn_w[DOUT + d];
        sj0 += (acc[nb][0] + bias[nb]) * aw[nb];
        sj1 += (acc[nb][1] + bias[nb]) * aw[nb];
        sj2 += (acc[nb][2] + bias[nb]) * aw[nb];
        sj3 += (acc[nb][3] + bias[nb]) * aw[nb];
    }
#pragma unroll
    for (int mk = 1; mk <= 8; mk <<= 1) {
        sj0 += __shfl_xor(sj0, mk, 64);
        sj1 += __shfl_xor(sj1, mk, 64);
        sj2 += __shfl_xor(sj2, mk, 64);
        sj3 += __shfl_xor(sj3, mk, 64);
    }
    float e0 = __expf(sj0), e1 = __expf(sj1), e2 = __expf(sj2), e3 = __expf(sj3);

    int slice = b * R_ + r;
    int js = n0 >> 5;
    int jhi = (n0 >> 4) & 1;
    int qp = jhi * 2 + (q >> 1);
    int jj0 = (q & 1) * 4;
    unsigned short* fb = fswz + ((long)(slice * 32 + js) * 16) * 512
                       + qp * 128 + m * 8 + jj0;
#pragma unroll
    for (int nb = 0; nb < 16; nb++) {
        ushort4 o;
        o.x = f2bf((acc[nb][0] + bias[nb]) * e0);
        o.y = f2bf((acc[nb][1] + bias[nb]) * e1);
        o.z = f2bf((acc[nb][2] + bias[nb]) * e2);
        o.w = f2bf((acc[nb][3] + bias[nb]) * e3);
        *(ushort4*)(fb + nb * 512) = o;
    }
    if (m == 0) {
        ushort4 o;
        o.x = f2bf(e0); o.y = f2bf(e1); o.z = f2bf(e2); o.w = f2bf(e3);
        *(ushort4*)(ebf + slice * N_ + n0 + q * 4) = o;
    }
}

// ---- k3 v4: barrier-free direct-L2, HAND-PIPELINED register double buffer --
// r4 post-mortem: v3's VGPR_Count=72 proved the compiler never allocated the
// 64 VGPRs needed to keep 16 G-fragment loads in flight -> near-serial L2
// latency chain (~7k cyc/step) at 2 waves/SIMD. v4 forces the ILP in source:
// bufA/bufB[16] (128 VGPRs, static-indexed named arrays per rule #20), s-loop
// unrolled x2 so the buffers swap roles with zero copies. Step s issues the 16
// b128 loads for s+1 BEFORE s's MFMAs (a full step ~400+ cyc covers ~225 cyc
// L2-hit latency; compiler's counted waitcnt only waits on the older group).
// adj: depth-2 parity-register prefetch (~2 steps ~ 1000 cyc covers ~900 cyc
// HBM latency). No barriers (e-table load is the only syncthreads); waves
// free-run. Budget: ~190 arch VGPR + 64 acc AGPR < 512 unified @ 2 waves/SIMD.
#define K3S(T_, CURB, NXTB, AJ0, AJ1)                                          \
  {                                                                            \
    i32x4 A0c = AJ0, A1c = AJ1;                                                \
    if ((T_) < 30) {  /* prefetch this parity's next step (T+2) */             \
      AJ0 = *(const i32x4*)(adjbase + ((T_) + 2) * 32);                        \
      AJ1 = *(const i32x4*)(adjbase + ((T_) + 2) * 32 + 4);                    \
    }                                                                          \
    if ((T_) < 31) {  /* issue next step's 16 G fragments into NXTB */         \
      const bf16x8* Gn = (const bf16x8*)(fsl + (size_t)((T_) + 1) * 8192) + lane; \
      _Pragma("unroll")                                                        \
      for (int nb = 0; nb < 16; nb++) NXTB[nb] = Gn[nb * 64];                  \
    }                                                                          \
    bf16x8 ev = *(const bf16x8*)(&Ebuf[(T_) * 32 + q * 8]);                    \
    int av[8] = {A0c.x, A0c.y, A0c.z, A0c.w, A1c.x, A1c.y, A1c.z, A1c.w};      \
    const int* ei = (const int*)&ev;                                           \
    bf16x8 af; int* afi = (int*)&af;                                           \
    _Pragma("unroll")                                                          \
    for (int p = 0; p < 4; p++) {                                              \
      unsigned int msk = (av[2 * p] ? 0xffffu : 0u)                            \
                       | (av[2 * p + 1] ? 0xffff0000u : 0u);                   \
      afi[p] = (int)(msk & 0x3F803F80u);  /* A entries: bf16 1.0 / 0.0 */      \
      int me = ei[p] & (int)msk;          /* masked e (bf16 pair) for l */     \
      union { int i; float f; } lo, hi;                                        \
      lo.i = me << 16; hi.i = me & (int)0xffff0000u;                           \
      l += lo.f + hi.f;                                                        \
    }                                                                          \
    _Pragma("unroll")                                                          \
    for (int nb = 0; nb < 16; nb++)                                            \
      acc[nb] = __builtin_amdgcn_mfma_f32_16x16x32_bf16(af, CURB[nb], acc[nb], 0, 0, 0); \
  }

__global__ __launch_bounds__(256, 2) void k3_attn(const int* __restrict__ adj,
        const unsigned short* __restrict__ fswz, const unsigned short* __restrict__ ebf,
        unsigned short* __restrict__ aggN) {
    __shared__ unsigned short Ebuf[1024];  // 2KB: full e table for this slice

    int bid = blockIdx.x;  // 512 = 32 slices x 16 i-tiles
    int slice = (bid & 7) * 4 + ((bid >> 3) & 3);  // XCD-affine slice grouping
    int it = bid >> 5;                             // 0..15 (64-row i-tile)
    int t = threadIdx.x, lane = t & 63, w = t >> 6;
    int m = lane & 15, q = lane >> 4;
    int i0 = it * 64 + w * 16;  // this wave's 16 rows, full j

    const unsigned short* fsl = fswz + (size_t)slice * (32 * 8192);
    const int* adjbase = adj + (size_t)slice * (N_ * N_)
                       + (size_t)(i0 + m) * N_ + q * 8;

    // e table: one cooperative copy + the only barrier in this kernel
    ((ushort4*)Ebuf)[t] = ((const ushort4*)(ebf + slice * N_))[t];
    __syncthreads();

    f32x4 acc[16];
#pragma unroll
    for (int i = 0; i < 16; i++) acc[i] = (f32x4)0.0f;
    float l = 0.f;

    // adj: depth-2 prefetch via parity registers (even steps / odd steps)
    i32x4 ajA_e = *(const i32x4*)(adjbase);
    i32x4 ajB_e = *(const i32x4*)(adjbase + 4);
    i32x4 ajA_o = *(const i32x4*)(adjbase + 32);
    i32x4 ajB_o = *(const i32x4*)(adjbase + 36);

    // G fragments: register double buffer, prologue fills bufA with step 0
    bf16x8 bufA[16], bufB[16];
    {
        const bf16x8* G0 = (const bf16x8*)fsl + lane;
#pragma unroll
        for (int nb = 0; nb < 16; nb++) bufA[nb] = G0[nb * 64];
    }

    for (int s = 0; s < 32; s += 2) {
        K3S(s,     bufA, bufB, ajA_e, ajB_e)
        K3S(s + 1, bufB, bufA, ajA_o, ajB_o)
    }

    // full denominator per row m: reduce over q (each wave has full j)
    l += __shfl_xor(l, 16, 64);
    l += __shfl_xor(l, 32, 64);
    float linv[4];
#pragma unroll
    for (int reg = 0; reg < 4; reg++) {
        float lr = __shfl(l, q * 4 + reg, 64);  // lane r<16 holds row r's l
        linv[reg] = (lr > 0.f) ? 1.0f / lr : 0.f;
    }
    // normalized aggN (bf16): row = i0 + q*4 + reg, col = nb*16 + m
    unsigned short* ob = aggN + ((size_t)(slice * N_ + i0 + q * 4)) * DOUT + m;
#pragma unroll
    for (int nb = 0; nb < 16; nb++) {
#pragma unroll
        for (int reg = 0; reg < 4; reg++)
            ob[(size_t)reg * DOUT + nb * 16] = f2bf(acc[nb][reg] * linv[reg]);
    }
}

// ---- k4: sum normalized per-relation agg, gate, write out -------------------
__global__ __launch_bounds__(256) void k4_out(const unsigned short* __restrict__ aggN,
        const float* __restrict__ gate_w, const float* __restrict__ gate_b,
        float* __restrict__ out) {
    __shared__ float red[4];
    int bid = blockIdx.x;  // 8192 = b*1024 + n
    int n = bid & 1023, b = bid >> 10;
    int d = threadIdx.x;
    float s = 0.f;
#pragma unroll
    for (int r = 0; r < R_; r++)
        s += bf2f(aggN[((size_t)((b * R_ + r) * N_ + n)) * DOUT + d]);
    float v = s * gate_w[d];
#pragma unroll
    for (int off = 32; off; off >>= 1) v += __shfl_down(v, off, 64);
    int lane = d & 63, wave = d >> 6;
    if (lane == 0) red[wave] = v;
    __syncthreads();
    float tot = red[0] + red[1] + red[2] + red[3];
    float g = 1.f / (1.f + __expf(-(tot + gate_b[0])));
    out[((size_t)(b * N_ + n)) * DOUT + d] = g * s;
}

extern "C" void kernel_launch(void* const* d_in, const int* in_sizes, int n_in,
                              void* d_out, int out_size, void* d_ws, size_t ws_size,
                              hipStream_t stream) {
    const float* node   = (const float*)d_in[0];
    const int*   adj    = (const int*)d_in[1];
    const float* rel_w  = (const float*)d_in[2];
    const float* rel_b  = (const float*)d_in[3];
    const float* attn_w = (const float*)d_in[4];
    // d_in[5] = attn_b: cancels in softmax, unused
    const float* gate_w = (const float*)d_in[6];
    const float* gate_b = (const float*)d_in[7];
    float* out = (float*)d_out;

    char* ws = (char*)d_ws;
    unsigned short* swzW = (unsigned short*)ws;                 // 524,288 B
    unsigned short* fswz = (unsigned short*)(ws + 524288);      // 16,777,216 B (G)
    unsigned short* ebf  = (unsigned short*)(ws + 17301504);    // 65,536 B
    unsigned short* aggN = (unsigned short*)(ws + 17367040);    // 16,777,216 B (bf16, normalized)

    k0_swz<<<128, 256, 0, stream>>>(rel_w, swzW);
    k1_proj<<<512, 256, 0, stream>>>(node, swzW, rel_b, attn_w, fswz, ebf);
    k3_attn<<<512, 256, 0, stream>>>(adj, fswz, ebf, aggN);
    k4_out<<<8192, 256, 0, stream>>>(aggN, gate_w, gate_b, out);
}

// Round 8
// 253.485 us; speedup vs baseline: 1.0935x; 1.0935x over previous
//
#include <hip/hip_runtime.h>
#include <hip/hip_bf16.h>

#define B_ 8
#define N_ 1024
#define DIN 256
#define DOUT 256
#define R_ 4

typedef __attribute__((ext_vector_type(8))) short bf16x8;
typedef __attribute__((ext_vector_type(4))) float f32x4;
typedef __attribute__((ext_vector_type(4))) int i32x4;

__device__ __forceinline__ unsigned short f2bf(float f) {
    union { float f; unsigned int u; } v; v.f = f;
    unsigned int u = v.u;
    u += 0x7fffu + ((u >> 16) & 1u);
    return (unsigned short)(u >> 16);
}
__device__ __forceinline__ float bf2f(unsigned short h) {
    union { float f; unsigned int u; } v; v.u = ((unsigned int)h) << 16;
    return v.f;
}

// async global->LDS, 16B/lane. LDS dest = wave-uniform base + lane*16.
__device__ __forceinline__ void gl_lds16(const void* g, void* l) {
    __builtin_amdgcn_global_load_lds(
        (const __attribute__((address_space(1))) unsigned int*)g,
        (__attribute__((address_space(3))) unsigned int*)l, 16, 0, 0);
}

// ---- k0: swizzle rel_w (f32 [R][D][K]) into bf16 MFMA B-fragment layout ----
__global__ __launch_bounds__(256) void k0_swz(const float* __restrict__ rw,
                                              unsigned short* __restrict__ swzW) {
    int t = blockIdx.x * 256 + threadIdx.x;  // 0..32767
    int lane = t & 63, nb = (t >> 6) & 15, ks = (t >> 10) & 7, r = t >> 13;
    int m = lane & 15, q = lane >> 4;
    const float* src = rw + ((r * DOUT + nb * 16 + m) * DIN) + ks * 32 + q * 8;
    float4 v0 = *(const float4*)src;
    float4 v1 = *(const float4*)(src + 4);
    bf16x8 o;
    o[0] = (short)f2bf(v0.x); o[1] = (short)f2bf(v0.y);
    o[2] = (short)f2bf(v0.z); o[3] = (short)f2bf(v0.w);
    o[4] = (short)f2bf(v1.x); o[5] = (short)f2bf(v1.y);
    o[6] = (short)f2bf(v1.z); o[7] = (short)f2bf(v1.w);
    *(bf16x8*)(swzW + (long)t * 8) = o;
}

// ---- k1: G[j][d] = e[j]*(node@rel_w^T + rel_b)[j][d], B-fragment layout -----
// e[j] = exp(sum_d feats[j][d]*attn_w[256+d]); also stores ebf (bf16 e).
__global__ __launch_bounds__(256) void k1_proj(const float* __restrict__ node,
        const unsigned short* __restrict__ swzW, const float* __restrict__ rel_b,
        const float* __restrict__ attn_w,
        unsigned short* __restrict__ fswz, unsigned short* __restrict__ ebf) {
    __shared__ unsigned short Wbuf[2][8192];
    int bid = blockIdx.x;
    int nt = bid & 15, r = (bid >> 4) & 3, b = bid >> 6;
    int w = threadIdx.x >> 6, lane = threadIdx.x & 63;
    int m = lane & 15, q = lane >> 4;
    int n0 = nt * 64 + w * 16;

    const float* Abase = node + ((b * N_ + n0 + m) * DIN) + q * 8;
    const unsigned short* Wsrc = swzW + r * 65536;

#pragma unroll
    for (int i = 0; i < 4; i++)
        gl_lds16(Wsrc + (w * 4 + i) * 512 + lane * 8, &Wbuf[0][(w * 4 + i) * 512]);

    f32x4 acc[16];
#pragma unroll
    for (int i = 0; i < 16; i++) acc[i] = (f32x4)0.0f;

    float4 a0 = *(const float4*)(Abase);
    float4 a1 = *(const float4*)(Abase + 4);

    for (int ks = 0; ks < 8; ks++) {
        int cur = ks & 1;
        __syncthreads();
        if (ks < 7) {
#pragma unroll
            for (int i = 0; i < 4; i++)
                gl_lds16(Wsrc + ((ks + 1) * 16 + w * 4 + i) * 512 + lane * 8,
                         &Wbuf[cur ^ 1][(w * 4 + i) * 512]);
        }
        bf16x8 af;
        af[0] = (short)f2bf(a0.x); af[1] = (short)f2bf(a0.y);
        af[2] = (short)f2bf(a0.z); af[3] = (short)f2bf(a0.w);
        af[4] = (short)f2bf(a1.x); af[5] = (short)f2bf(a1.y);
        af[6] = (short)f2bf(a1.z); af[7] = (short)f2bf(a1.w);
        if (ks < 7) {
            a0 = *(const float4*)(Abase + (ks + 1) * 32);
            a1 = *(const float4*)(Abase + (ks + 1) * 32 + 4);
        }
#pragma unroll
        for (int nb = 0; nb < 16; nb++) {
            bf16x8 wf = *(const bf16x8*)(&Wbuf[cur][nb * 512 + lane * 8]);
            acc[nb] = __builtin_amdgcn_mfma_f32_16x16x32_bf16(af, wf, acc[nb], 0, 0, 0);
        }
    }

    // C layout: row j = n0 + q*4 + reg, col d = nb*16 + m.
    float sj0 = 0.f, sj1 = 0.f, sj2 = 0.f, sj3 = 0.f;
    float bias[16], aw[16];
#pragma unroll
    for (int nb = 0; nb < 16; nb++) {
        int d = nb * 16 + m;
        bias[nb] = rel_b[r * DOUT + d];
        aw[nb] = attn_w[DOUT + d];
        sj0 += (acc[nb][0] + bias[nb]) * aw[nb];
        sj1 += (acc[nb][1] + bias[nb]) * aw[nb];
        sj2 += (acc[nb][2] + bias[nb]) * aw[nb];
        sj3 += (acc[nb][3] + bias[nb]) * aw[nb];
    }
#pragma unroll
    for (int mk = 1; mk <= 8; mk <<= 1) {
        sj0 += __shfl_xor(sj0, mk, 64);
        sj1 += __shfl_xor(sj1, mk, 64);
        sj2 += __shfl_xor(sj2, mk, 64);
        sj3 += __shfl_xor(sj3, mk, 64);
    }
    float e0 = __expf(sj0), e1 = __expf(sj1), e2 = __expf(sj2), e3 = __expf(sj3);

    int slice = b * R_ + r;
    int js = n0 >> 5;
    int jhi = (n0 >> 4) & 1;
    int qp = jhi * 2 + (q >> 1);
    int jj0 = (q & 1) * 4;
    unsigned short* fb = fswz + ((long)(slice * 32 + js) * 16) * 512
                       + qp * 128 + m * 8 + jj0;
#pragma unroll
    for (int nb = 0; nb < 16; nb++) {
        ushort4 o;
        o.x = f2bf((acc[nb][0] + bias[nb]) * e0);
        o.y = f2bf((acc[nb][1] + bias[nb]) * e1);
        o.z = f2bf((acc[nb][2] + bias[nb]) * e2);
        o.w = f2bf((acc[nb][3] + bias[nb]) * e3);
        *(ushort4*)(fb + nb * 512) = o;
    }
    if (m == 0) {
        ushort4 o;
        o.x = f2bf(e0); o.y = f2bf(e1); o.z = f2bf(e2); o.w = f2bf(e3);
        *(ushort4*)(ebf + slice * N_ + n0 + q * 4) = o;
    }
}

// ---- k3 v7: r3's VERIFIED 4-slot counted-vmcnt ring + LDS-packed adj -------
// Skeleton identical to r3 (the only structure that beat baseline, refcheck'd
// and 75us): 4x16KB G ring, prefetch distance 2, per-step {wait; s_barrier;
// sched_barrier; prefetch; compute}. One change: adjacency is bit-packed into
// 8.25KB LDS in the prologue (each block's 64rows x 1024j tile), so the main
// loop has ZERO global adj loads -> VMEM groups are the 4 gl_lds16 only.
// vmcnt math (in-order retire, m135): at top of step t, flying = g(t)+g(t+1)
// = 8 ops -> vmcnt(4) retires exactly g(t) BEFORE s_barrier. Tail: 4,4,4,0.
// WAR slack unchanged from r3: slot (t+2)%4 overwritten at step t; last read
// at t-2; two barriers separate them. Abits row stride 33 words -> loop mask
// read (16 rows/wave, 4 lanes broadcast each) is conflict-free.
#define K3_STEP(T_, SLOT_, PFSLOT_, DO_PF_, WAITN_)                            \
  {                                                                            \
    asm volatile("s_waitcnt vmcnt(" #WAITN_ ")" ::: "memory");                 \
    __builtin_amdgcn_s_barrier();                                              \
    __builtin_amdgcn_sched_barrier(0);                                         \
    if (DO_PF_) {                                                              \
      _Pragma("unroll")                                                        \
      for (int i = 0; i < 4; i++)                                              \
        gl_lds16(fsl + (size_t)((T_) + 2) * 8192 + (w * 4 + i) * 512 + lane * 8, \
                 &Gbuf[PFSLOT_][(w * 4 + i) * 512]);                           \
    }                                                                          \
    bf16x8 ev = *(const bf16x8*)(&Ebuf[(T_) * 32 + q * 8]);                    \
    unsigned int aw_ = AbitsW[(w * 16 + m) * 33 + (T_)];                       \
    unsigned int ab_ = (aw_ >> (q * 8)) & 0xffu;                               \
    const int* ei = (const int*)&ev;                                           \
    bf16x8 af; int* afi = (int*)&af;                                           \
    _Pragma("unroll")                                                          \
    for (int p = 0; p < 4; p++) {                                              \
      unsigned int msk = (((ab_ >> (2 * p)) & 1u) ? 0xffffu : 0u)              \
                       | (((ab_ >> (2 * p + 1)) & 1u) ? 0xffff0000u : 0u);     \
      afi[p] = (int)(msk & 0x3F803F80u);  /* A entries: bf16 1.0 / 0.0 */      \
      int me = ei[p] & (int)msk;          /* masked e (bf16 pair) for l */     \
      union { int i; float f; } lo, hi;                                        \
      lo.i = me << 16; hi.i = me & (int)0xffff0000u;                           \
      l += lo.f + hi.f;                                                        \
    }                                                                          \
    const unsigned short* Gb = &Gbuf[SLOT_][lane * 8];                         \
    _Pragma("unroll")                                                          \
    for (int nb = 0; nb < 16; nb++) {                                          \
      bf16x8 bfq = *(const bf16x8*)(Gb + nb * 512);                            \
      acc[nb] = __builtin_amdgcn_mfma_f32_16x16x32_bf16(af, bfq, acc[nb], 0, 0, 0); \
    }                                                                          \
  }

__global__ __launch_bounds__(256, 2) void k3_attn(const int* __restrict__ adj,
        const unsigned short* __restrict__ fswz, const unsigned short* __restrict__ ebf,
        unsigned short* __restrict__ aggN) {
    __shared__ unsigned short Gbuf[4][8192];  // 4 x 16KB ring
    __shared__ unsigned short Ebuf[1024];     // 2KB: full e table for this slice
    __shared__ unsigned int AbitsW[64 * 33];  // 8.25KB: packed adj bits

    int bid = blockIdx.x;  // 512 = 32 slices x 16 i-tiles
    int slice = (bid & 7) * 4 + ((bid >> 3) & 3);  // XCD-affine slice grouping
    int it = bid >> 5;                             // 0..15 (64-row i-tile)
    int t = threadIdx.x, lane = t & 63, w = t >> 6;
    int m = lane & 15, q = lane >> 4;
    int i0 = it * 64 + w * 16;  // this wave's 16 rows

    const unsigned short* fsl = fswz + (size_t)slice * (32 * 8192);

    // ---- prologue A: e-table (plain copy) + adj bit-pack into LDS ----------
    ((ushort4*)Ebuf)[t] = ((const ushort4*)(ebf + slice * N_))[t];

    // wave w packs its own 16 rows. Lane l covers j = l*16 .. l*16+15 of each
    // row (4 contiguous-dwordx4 spans; L2 coalesces the 64B lane stride).
    // bit (j&31) of word (j>>5): even lane -> bits 0..15, odd -> 16..31.
    {
        const int* arow = adj + (size_t)slice * (N_ * N_) + (size_t)i0 * N_;
        for (int r = 0; r < 16; r++) {
            const int* rp = arow + (size_t)r * N_ + lane * 16;
            i32x4 c0 = *(const i32x4*)(rp);
            i32x4 c1 = *(const i32x4*)(rp + 4);
            i32x4 c2 = *(const i32x4*)(rp + 8);
            i32x4 c3 = *(const i32x4*)(rp + 12);
            unsigned int bits =
                  (c0.x ? 0x0001u : 0u) | (c0.y ? 0x0002u : 0u)
                | (c0.z ? 0x0004u : 0u) | (c0.w ? 0x0008u : 0u)
                | (c1.x ? 0x0010u : 0u) | (c1.y ? 0x0020u : 0u)
                | (c1.z ? 0x0040u : 0u) | (c1.w ? 0x0080u : 0u)
                | (c2.x ? 0x0100u : 0u) | (c2.y ? 0x0200u : 0u)
                | (c2.z ? 0x0400u : 0u) | (c2.w ? 0x0800u : 0u)
                | (c3.x ? 0x1000u : 0u) | (c3.y ? 0x2000u : 0u)
                | (c3.z ? 0x4000u : 0u) | (c3.w ? 0x8000u : 0u);
            unsigned int other = __shfl_xor((int)bits, 1, 64);
            if (!(lane & 1))
                AbitsW[(w * 16 + r) * 33 + (lane >> 1)] = bits | (other << 16);
        }
    }

    __syncthreads();  // full drain: vmcnt accounting starts from zero

    // ---- prologue B: stage G steps 0,1 (groups of 4 per wave) --------------
#pragma unroll
    for (int i = 0; i < 4; i++)
        gl_lds16(fsl + (w * 4 + i) * 512 + lane * 8, &Gbuf[0][(w * 4 + i) * 512]);
#pragma unroll
    for (int i = 0; i < 4; i++)
        gl_lds16(fsl + 8192 + (w * 4 + i) * 512 + lane * 8, &Gbuf[1][(w * 4 + i) * 512]);

    f32x4 acc[16];
#pragma unroll
    for (int i = 0; i < 16; i++) acc[i] = (f32x4)0.0f;
    float l = 0.f;

    for (int tt = 0; tt < 28; tt += 4) {  // tt multiple of 4 -> slots static
        K3_STEP(tt + 0, 0, 2, 1, 4)
        K3_STEP(tt + 1, 1, 3, 1, 4)
        K3_STEP(tt + 2, 2, 0, 1, 4)
        K3_STEP(tt + 3, 3, 1, 1, 4)
    }
    K3_STEP(28, 0, 2, 1, 4)
    K3_STEP(29, 1, 3, 1, 4)
    K3_STEP(30, 2, 0, 0, 4)
    K3_STEP(31, 3, 0, 0, 0)

    // full denominator per row m: reduce over q (each wave has full j)
    l += __shfl_xor(l, 16, 64);
    l += __shfl_xor(l, 32, 64);
    float linv[4];
#pragma unroll
    for (int reg = 0; reg < 4; reg++) {
        float lr = __shfl(l, q * 4 + reg, 64);  // lane r<16 holds row r's l
        linv[reg] = (lr > 0.f) ? 1.0f / lr : 0.f;
    }
    // normalized aggN (bf16): row = i0 + q*4 + reg, col = nb*16 + m
    unsigned short* ob = aggN + ((size_t)(slice * N_ + i0 + q * 4)) * DOUT + m;
#pragma unroll
    for (int nb = 0; nb < 16; nb++) {
#pragma unroll
        for (int reg = 0; reg < 4; reg++)
            ob[(size_t)reg * DOUT + nb * 16] = f2bf(acc[nb][reg] * linv[reg]);
    }
}

// ---- k4: sum normalized per-relation agg, gate, write out -------------------
__global__ __launch_bounds__(256) void k4_out(const unsigned short* __restrict__ aggN,
        const float* __restrict__ gate_w, const float* __restrict__ gate_b,
        float* __restrict__ out) {
    __shared__ float red[4];
    int bid = blockIdx.x;  // 8192 = b*1024 + n
    int n = bid & 1023, b = bid >> 10;
    int d = threadIdx.x;
    float s = 0.f;
#pragma unroll
    for (int r = 0; r < R_; r++)
        s += bf2f(aggN[((size_t)((b * R_ + r) * N_ + n)) * DOUT + d]);
    float v = s * gate_w[d];
#pragma unroll
    for (int off = 32; off; off >>= 1) v += __shfl_down(v, off, 64);
    int lane = d & 63, wave = d >> 6;
    if (lane == 0) red[wave] = v;
    __syncthreads();
    float tot = red[0] + red[1] + red[2] + red[3];
    float g = 1.f / (1.f + __expf(-(tot + gate_b[0])));
    out[((size_t)(b * N_ + n)) * DOUT + d] = g * s;
}

extern "C" void kernel_launch(void* const* d_in, const int* in_sizes, int n_in,
                              void* d_out, int out_size, void* d_ws, size_t ws_size,
                              hipStream_t stream) {
    const float* node   = (const float*)d_in[0];
    const int*   adj    = (const int*)d_in[1];
    const float* rel_w  = (const float*)d_in[2];
    const float* rel_b  = (const float*)d_in[3];
    const float* attn_w = (const float*)d_in[4];
    // d_in[5] = attn_b: cancels in softmax, unused
    const float* gate_w = (const float*)d_in[6];
    const float* gate_b = (const float*)d_in[7];
    float* out = (float*)d_out;

    char* ws = (char*)d_ws;
    unsigned short* swzW = (unsigned short*)ws;                 // 524,288 B
    unsigned short* fswz = (unsigned short*)(ws + 524288);      // 16,777,216 B (G)
    unsigned short* ebf  = (unsigned short*)(ws + 17301504);    // 65,536 B
    unsigned short* aggN = (unsigned short*)(ws + 17367040);    // 16,777,216 B (bf16, normalized)

    k0_swz<<<128, 256, 0, stream>>>(rel_w, swzW);
    k1_proj<<<512, 256, 0, stream>>>(node, swzW, rel_b, attn_w, fswz, ebf);
    k3_attn<<<512, 256, 0, stream>>>(adj, fswz, ebf, aggN);
    k4_out<<<8192, 256, 0, stream>>>(aggN, gate_w, gate_b, out);
}

// Round 9
// 251.565 us; speedup vs baseline: 1.1019x; 1.0076x over previous
//
#include <hip/hip_runtime.h>
#include <hip/hip_bf16.h>

#define B_ 8
#define N_ 1024
#define DIN 256
#define DOUT 256
#define R_ 4

typedef __attribute__((ext_vector_type(8))) short bf16x8;
typedef __attribute__((ext_vector_type(4))) float f32x4;
typedef __attribute__((ext_vector_type(4))) int i32x4;

__device__ __forceinline__ unsigned short f2bf(float f) {
    union { float f; unsigned int u; } v; v.f = f;
    unsigned int u = v.u;
    u += 0x7fffu + ((u >> 16) & 1u);
    return (unsigned short)(u >> 16);
}
__device__ __forceinline__ float bf2f(unsigned short h) {
    union { float f; unsigned int u; } v; v.u = ((unsigned int)h) << 16;
    return v.f;
}

// async global->LDS, 16B/lane. LDS dest = wave-uniform base + lane*16.
__device__ __forceinline__ void gl_lds16(const void* g, void* l) {
    __builtin_amdgcn_global_load_lds(
        (const __attribute__((address_space(1))) unsigned int*)g,
        (__attribute__((address_space(3))) unsigned int*)l, 16, 0, 0);
}

// raw global 16B load: fixed issue position (exact vmcnt counting).
__device__ __forceinline__ i32x4 gload4(const void* p) {
    i32x4 r;
    asm volatile("global_load_dwordx4 %0, %1, off" : "=v"(r) : "v"(p) : "memory");
    return r;
}

// ---- k0: swizzle rel_w (f32 [R][D][K]) into bf16 MFMA B-fragment layout ----
__global__ __launch_bounds__(256) void k0_swz(const float* __restrict__ rw,
                                              unsigned short* __restrict__ swzW) {
    int t = blockIdx.x * 256 + threadIdx.x;  // 0..32767
    int lane = t & 63, nb = (t >> 6) & 15, ks = (t >> 10) & 7, r = t >> 13;
    int m = lane & 15, q = lane >> 4;
    const float* src = rw + ((r * DOUT + nb * 16 + m) * DIN) + ks * 32 + q * 8;
    float4 v0 = *(const float4*)src;
    float4 v1 = *(const float4*)(src + 4);
    bf16x8 o;
    o[0] = (short)f2bf(v0.x); o[1] = (short)f2bf(v0.y);
    o[2] = (short)f2bf(v0.z); o[3] = (short)f2bf(v0.w);
    o[4] = (short)f2bf(v1.x); o[5] = (short)f2bf(v1.y);
    o[6] = (short)f2bf(v1.z); o[7] = (short)f2bf(v1.w);
    *(bf16x8*)(swzW + (long)t * 8) = o;
}

// ---- k1: G[j][d] = e[j]*(node@rel_w^T + rel_b)[j][d], B-fragment layout -----
// e[j] = exp(sum_d feats[j][d]*attn_w[256+d]); also stores ebf (bf16 e).
__global__ __launch_bounds__(256) void k1_proj(const float* __restrict__ node,
        const unsigned short* __restrict__ swzW, const float* __restrict__ rel_b,
        const float* __restrict__ attn_w,
        unsigned short* __restrict__ fswz, unsigned short* __restrict__ ebf) {
    __shared__ unsigned short Wbuf[2][8192];
    int bid = blockIdx.x;
    int nt = bid & 15, r = (bid >> 4) & 3, b = bid >> 6;
    int w = threadIdx.x >> 6, lane = threadIdx.x & 63;
    int m = lane & 15, q = lane >> 4;
    int n0 = nt * 64 + w * 16;

    const float* Abase = node + ((b * N_ + n0 + m) * DIN) + q * 8;
    const unsigned short* Wsrc = swzW + r * 65536;

#pragma unroll
    for (int i = 0; i < 4; i++)
        gl_lds16(Wsrc + (w * 4 + i) * 512 + lane * 8, &Wbuf[0][(w * 4 + i) * 512]);

    f32x4 acc[16];
#pragma unroll
    for (int i = 0; i < 16; i++) acc[i] = (f32x4)0.0f;

    float4 a0 = *(const float4*)(Abase);
    float4 a1 = *(const float4*)(Abase + 4);

    for (int ks = 0; ks < 8; ks++) {
        int cur = ks & 1;
        __syncthreads();
        if (ks < 7) {
#pragma unroll
            for (int i = 0; i < 4; i++)
                gl_lds16(Wsrc + ((ks + 1) * 16 + w * 4 + i) * 512 + lane * 8,
                         &Wbuf[cur ^ 1][(w * 4 + i) * 512]);
        }
        bf16x8 af;
        af[0] = (short)f2bf(a0.x); af[1] = (short)f2bf(a0.y);
        af[2] = (short)f2bf(a0.z); af[3] = (short)f2bf(a0.w);
        af[4] = (short)f2bf(a1.x); af[5] = (short)f2bf(a1.y);
        af[6] = (short)f2bf(a1.z); af[7] = (short)f2bf(a1.w);
        if (ks < 7) {
            a0 = *(const float4*)(Abase + (ks + 1) * 32);
            a1 = *(const float4*)(Abase + (ks + 1) * 32 + 4);
        }
#pragma unroll
        for (int nb = 0; nb < 16; nb++) {
            bf16x8 wf = *(const bf16x8*)(&Wbuf[cur][nb * 512 + lane * 8]);
            acc[nb] = __builtin_amdgcn_mfma_f32_16x16x32_bf16(af, wf, acc[nb], 0, 0, 0);
        }
    }

    // C layout: row j = n0 + q*4 + reg, col d = nb*16 + m.
    float sj0 = 0.f, sj1 = 0.f, sj2 = 0.f, sj3 = 0.f;
    float bias[16], aw[16];
#pragma unroll
    for (int nb = 0; nb < 16; nb++) {
        int d = nb * 16 + m;
        bias[nb] = rel_b[r * DOUT + d];
        aw[nb] = attn_w[DOUT + d];
        sj0 += (acc[nb][0] + bias[nb]) * aw[nb];
        sj1 += (acc[nb][1] + bias[nb]) * aw[nb];
        sj2 += (acc[nb][2] + bias[nb]) * aw[nb];
        sj3 += (acc[nb][3] + bias[nb]) * aw[nb];
    }
#pragma unroll
    for (int mk = 1; mk <= 8; mk <<= 1) {
        sj0 += __shfl_xor(sj0, mk, 64);
        sj1 += __shfl_xor(sj1, mk, 64);
        sj2 += __shfl_xor(sj2, mk, 64);
        sj3 += __shfl_xor(sj3, mk, 64);
    }
    float e0 = __expf(sj0), e1 = __expf(sj1), e2 = __expf(sj2), e3 = __expf(sj3);

    int slice = b * R_ + r;
    int js = n0 >> 5;
    int jhi = (n0 >> 4) & 1;
    int qp = jhi * 2 + (q >> 1);
    int jj0 = (q & 1) * 4;
    unsigned short* fb = fswz + ((long)(slice * 32 + js) * 16) * 512
                       + qp * 128 + m * 8 + jj0;
#pragma unroll
    for (int nb = 0; nb < 16; nb++) {
        ushort4 o;
        o.x = f2bf((acc[nb][0] + bias[nb]) * e0);
        o.y = f2bf((acc[nb][1] + bias[nb]) * e1);
        o.z = f2bf((acc[nb][2] + bias[nb]) * e2);
        o.w = f2bf((acc[nb][3] + bias[nb]) * e3);
        *(ushort4*)(fb + nb * 512) = o;
    }
    if (m == 0) {
        ushort4 o;
        o.x = f2bf(e0); o.y = f2bf(e1); o.z = f2bf(e2); o.w = f2bf(e3);
        *(ushort4*)(ebf + slice * N_ + n0 + q * 4) = o;
    }
}

// ---- k3 v8: r3's verified ring + 2 row-groups/wave (B-frag reuse x2) -------
// Diagnosis (r2..r8): every pipe <15% busy, step ~2930cyc vs m97's ~700 on
// the same skeleton; the structural gap is reads-per-MFMA (ours 1:1, m97 1:2).
// v8: wave owns 32 rows as two 16-row groups; each ds_read_b128 B-fragment
// feeds TWO MFMAs (mask af0/af1 per group). Blocks = 128-row tiles, grid 256.
// Per MAC: LDS reads, staging traffic (G re-read 8x not 16x) and adj loads
// all halve; MFMA/VALU double (both idle-rich). Ring skeleton byte-identical
// to r3: 4x16KB slots, distance 2, {vmcnt(N); s_barrier; sched_barrier;
// prefetch; compute}. VMEM group = 4 gl_lds16 + 4 adj = 8 ops; at top of
// step t flying = g(t)+g(t+1) = 16 -> vmcnt(8) retires exactly g(t)
// (in-order retire, m135). Tail 8,8,8,0. NO launch_bounds cap beyond
// (256,1): hand-vmcnt requires zero spill (r5's failure: (256,3) VGPR cap
// -> spill ops entered the vmcnt stream -> counts wrong -> absmax 6.15).
#define K3_STEP(T_, SLOT_, PFSLOT_, DO_PF_, WAITN_)                            \
  {                                                                            \
    asm volatile("s_waitcnt vmcnt(" #WAITN_ ")" ::: "memory");                 \
    __builtin_amdgcn_s_barrier();                                              \
    __builtin_amdgcn_sched_barrier(0);                                         \
    if (DO_PF_) {                                                              \
      _Pragma("unroll")                                                        \
      for (int i = 0; i < 4; i++)                                              \
        gl_lds16(fsl + (size_t)((T_) + 2) * 8192 + (w * 4 + i) * 512 + lane * 8, \
                 &Gbuf[PFSLOT_][(w * 4 + i) * 512]);                           \
      adj0A[PFSLOT_] = gload4(adjb0 + ((T_) + 2) * 32);                        \
      adj0B[PFSLOT_] = gload4(adjb0 + ((T_) + 2) * 32 + 4);                    \
      adj1A[PFSLOT_] = gload4(adjb1 + ((T_) + 2) * 32);                        \
      adj1B[PFSLOT_] = gload4(adjb1 + ((T_) + 2) * 32 + 4);                    \
    }                                                                          \
    bf16x8 ev = *(const bf16x8*)(&Ebuf[(T_) * 32 + q * 8]);                    \
    const int* ei = (const int*)&ev;                                           \
    i32x4 C0a = adj0A[SLOT_], C0b = adj0B[SLOT_];                              \
    i32x4 C1a = adj1A[SLOT_], C1b = adj1B[SLOT_];                              \
    int av0[8] = {C0a.x, C0a.y, C0a.z, C0a.w, C0b.x, C0b.y, C0b.z, C0b.w};     \
    int av1[8] = {C1a.x, C1a.y, C1a.z, C1a.w, C1b.x, C1b.y, C1b.z, C1b.w};     \
    bf16x8 af0, af1; int* af0i = (int*)&af0; int* af1i = (int*)&af1;           \
    _Pragma("unroll")                                                          \
    for (int p = 0; p < 4; p++) {                                              \
      unsigned int m0 = (av0[2 * p] ? 0xffffu : 0u)                            \
                      | (av0[2 * p + 1] ? 0xffff0000u : 0u);                   \
      unsigned int m1 = (av1[2 * p] ? 0xffffu : 0u)                            \
                      | (av1[2 * p + 1] ? 0xffff0000u : 0u);                   \
      af0i[p] = (int)(m0 & 0x3F803F80u);  /* bf16 1.0 / 0.0 */                 \
      af1i[p] = (int)(m1 & 0x3F803F80u);                                       \
      int me0 = ei[p] & (int)m0;                                               \
      int me1 = ei[p] & (int)m1;                                               \
      union { int i; float f; } a, b, c, d;                                    \
      a.i = me0 << 16; b.i = me0 & (int)0xffff0000u;                           \
      c.i = me1 << 16; d.i = me1 & (int)0xffff0000u;                           \
      l0 += a.f + b.f;                                                         \
      l1 += c.f + d.f;                                                         \
    }                                                                          \
    const unsigned short* Gb = &Gbuf[SLOT_][lane * 8];                         \
    _Pragma("unroll")                                                          \
    for (int nb = 0; nb < 16; nb++) {                                          \
      bf16x8 bfq = *(const bf16x8*)(Gb + nb * 512);                            \
      acc0[nb] = __builtin_amdgcn_mfma_f32_16x16x32_bf16(af0, bfq, acc0[nb], 0, 0, 0); \
      acc1[nb] = __builtin_amdgcn_mfma_f32_16x16x32_bf16(af1, bfq, acc1[nb], 0, 0, 0); \
    }                                                                          \
  }

__global__ __launch_bounds__(256, 1) void k3_attn(const int* __restrict__ adj,
        const unsigned short* __restrict__ fswz, const unsigned short* __restrict__ ebf,
        unsigned short* __restrict__ aggN) {
    __shared__ unsigned short Gbuf[4][8192];  // 4 x 16KB ring
    __shared__ unsigned short Ebuf[1024];     // 2KB: full e table for this slice

    int bid = blockIdx.x;  // 256 = 32 slices x 8 i-tiles (128 rows each)
    int slice = (bid & 7) * 4 + ((bid >> 3) & 3);  // XCD-affine slice grouping
    int it = bid >> 5;                             // 0..7
    int t = threadIdx.x, lane = t & 63, w = t >> 6;
    int m = lane & 15, q = lane >> 4;
    int i0 = it * 128 + w * 32;  // this wave's 32 rows (two 16-row groups)

    const unsigned short* fsl = fswz + (size_t)slice * (32 * 8192);
    const int* adjb0 = adj + (size_t)slice * (N_ * N_)
                     + (size_t)(i0 + m) * N_ + q * 8;        // group 0 rows
    const int* adjb1 = adjb0 + (size_t)16 * N_;              // group 1 rows

    // e table: plain copy; __syncthreads drains all counters so the loop's
    // manual vmcnt accounting starts from zero (r7-verified prologue).
    ((ushort4*)Ebuf)[t] = ((const ushort4*)(ebf + slice * N_))[t];
    __syncthreads();

    i32x4 adj0A[4], adj0B[4], adj1A[4], adj1B[4];

    // prologue: [stage(0) x4, adj(0) x4] then [stage(1) x4, adj(1) x4]
#pragma unroll
    for (int i = 0; i < 4; i++)
        gl_lds16(fsl + (w * 4 + i) * 512 + lane * 8, &Gbuf[0][(w * 4 + i) * 512]);
    adj0A[0] = gload4(adjb0);
    adj0B[0] = gload4(adjb0 + 4);
    adj1A[0] = gload4(adjb1);
    adj1B[0] = gload4(adjb1 + 4);
#pragma unroll
    for (int i = 0; i < 4; i++)
        gl_lds16(fsl + 8192 + (w * 4 + i) * 512 + lane * 8, &Gbuf[1][(w * 4 + i) * 512]);
    adj0A[1] = gload4(adjb0 + 32);
    adj0B[1] = gload4(adjb0 + 36);
    adj1A[1] = gload4(adjb1 + 32);
    adj1B[1] = gload4(adjb1 + 36);

    f32x4 acc0[16], acc1[16];
#pragma unroll
    for (int i = 0; i < 16; i++) { acc0[i] = (f32x4)0.0f; acc1[i] = (f32x4)0.0f; }
    float l0 = 0.f, l1 = 0.f;

    for (int tt = 0; tt < 28; tt += 4) {  // tt multiple of 4 -> slots static
        K3_STEP(tt + 0, 0, 2, 1, 8)
        K3_STEP(tt + 1, 1, 3, 1, 8)
        K3_STEP(tt + 2, 2, 0, 1, 8)
        K3_STEP(tt + 3, 3, 1, 1, 8)
    }
    K3_STEP(28, 0, 2, 1, 8)
    K3_STEP(29, 1, 3, 1, 8)
    K3_STEP(30, 2, 0, 0, 8)
    K3_STEP(31, 3, 0, 0, 0)

    // full denominators per row m (reduce over q), per group
    l0 += __shfl_xor(l0, 16, 64);
    l0 += __shfl_xor(l0, 32, 64);
    l1 += __shfl_xor(l1, 16, 64);
    l1 += __shfl_xor(l1, 32, 64);
    float linv0[4], linv1[4];
#pragma unroll
    for (int reg = 0; reg < 4; reg++) {
        float r0 = __shfl(l0, q * 4 + reg, 64);  // lane r<16 holds row r's l
        float r1 = __shfl(l1, q * 4 + reg, 64);
        linv0[reg] = (r0 > 0.f) ? 1.0f / r0 : 0.f;
        linv1[reg] = (r1 > 0.f) ? 1.0f / r1 : 0.f;
    }
    // normalized aggN (bf16): group h row = i0 + h*16 + q*4 + reg, col = nb*16+m
    unsigned short* ob0 = aggN + ((size_t)(slice * N_ + i0 + q * 4)) * DOUT + m;
    unsigned short* ob1 = ob0 + (size_t)16 * DOUT;
#pragma unroll
    for (int nb = 0; nb < 16; nb++) {
#pragma unroll
        for (int reg = 0; reg < 4; reg++) {
            ob0[(size_t)reg * DOUT + nb * 16] = f2bf(acc0[nb][reg] * linv0[reg]);
            ob1[(size_t)reg * DOUT + nb * 16] = f2bf(acc1[nb][reg] * linv1[reg]);
        }
    }
}

// ---- k4: sum normalized per-relation agg, gate, write out -------------------
__global__ __launch_bounds__(256) void k4_out(const unsigned short* __restrict__ aggN,
        const float* __restrict__ gate_w, const float* __restrict__ gate_b,
        float* __restrict__ out) {
    __shared__ float red[4];
    int bid = blockIdx.x;  // 8192 = b*1024 + n
    int n = bid & 1023, b = bid >> 10;
    int d = threadIdx.x;
    float s = 0.f;
#pragma unroll
    for (int r = 0; r < R_; r++)
        s += bf2f(aggN[((size_t)((b * R_ + r) * N_ + n)) * DOUT + d]);
    float v = s * gate_w[d];
#pragma unroll
    for (int off = 32; off; off >>= 1) v += __shfl_down(v, off, 64);
    int lane = d & 63, wave = d >> 6;
    if (lane == 0) red[wave] = v;
    __syncthreads();
    float tot = red[0] + red[1] + red[2] + red[3];
    float g = 1.f / (1.f + __expf(-(tot + gate_b[0])));
    out[((size_t)(b * N_ + n)) * DOUT + d] = g * s;
}

extern "C" void kernel_launch(void* const* d_in, const int* in_sizes, int n_in,
                              void* d_out, int out_size, void* d_ws, size_t ws_size,
                              hipStream_t stream) {
    const float* node   = (const float*)d_in[0];
    const int*   adj    = (const int*)d_in[1];
    const float* rel_w  = (const float*)d_in[2];
    const float* rel_b  = (const float*)d_in[3];
    const float* attn_w = (const float*)d_in[4];
    // d_in[5] = attn_b: cancels in softmax, unused
    const float* gate_w = (const float*)d_in[6];
    const float* gate_b = (const float*)d_in[7];
    float* out = (float*)d_out;

    char* ws = (char*)d_ws;
    unsigned short* swzW = (unsigned short*)ws;                 // 524,288 B
    unsigned short* fswz = (unsigned short*)(ws + 524288);      // 16,777,216 B (G)
    unsigned short* ebf  = (unsigned short*)(ws + 17301504);    // 65,536 B
    unsigned short* aggN = (unsigned short*)(ws + 17367040);    // 16,777,216 B (bf16, normalized)

    k0_swz<<<128, 256, 0, stream>>>(rel_w, swzW);
    k1_proj<<<512, 256, 0, stream>>>(node, swzW, rel_b, attn_w, fswz, ebf);
    k3_attn<<<256, 256, 0, stream>>>(adj, fswz, ebf, aggN);
    k4_out<<<8192, 256, 0, stream>>>(aggN, gate_w, gate_b, out);
}